// Round 1
// baseline (556.289 us; speedup 1.0000x reference)
//
#include <hip/hip_runtime.h>

#define Bsz 512
#define Lsz 512
#define Tsz 128
#define TAG_START 126
#define TAG_STOP 127
#define NEGV (-10000.0f)

__device__ __forceinline__ float wave_max(float v) {
  #pragma unroll
  for (int off = 32; off > 0; off >>= 1) v = fmaxf(v, __shfl_down(v, off, 64));
  return v;
}
__device__ __forceinline__ float wave_sum(float v) {
  #pragma unroll
  for (int off = 32; off > 0; off >>= 1) v += __shfl_down(v, off, 64);
  return v;
}

// One block per batch element, 128 threads (thread = "next" tag).
// expT row held in 128 VGPRs; u vector broadcast from LDS (double-buffered,
// one barrier per timestep); lagged shift m avoids a per-step max-reduction.
__global__ __launch_bounds__(Tsz) void crf_forward_kernel(
    const float* __restrict__ feats, const float* __restrict__ trans,
    const int* __restrict__ lens, float* __restrict__ fwd_out)
{
  __shared__ float u_buf[2][Tsz];
  __shared__ float m_slot[2];
  __shared__ float wred[2];

  const int b = blockIdx.x;
  const int tid = threadIdx.x;
  const int len = lens[b];
  const float* fb = feats + (size_t)b * Lsz * Tsz;

  // expT[next][prev] = exp(trans[next][prev]) into registers (128 VGPRs)
  float er[Tsz];
  {
    const float4* t4 = (const float4*)(trans + tid * Tsz);
    #pragma unroll
    for (int j = 0; j < Tsz / 4; ++j) {
      float4 v = t4[j];
      er[4*j+0] = __expf(v.x);
      er[4*j+1] = __expf(v.y);
      er[4*j+2] = __expf(v.z);
      er[4*j+3] = __expf(v.w);
    }
  }

  float fv = (tid == TAG_START) ? 0.0f : NEGV;
  float m  = 0.0f;          // shift; exact identity holds for any m, only range matters
  float e_cur = fb[tid];    // emit for t=0
  int buf = 0;

  for (int t = 0; t < len; ++t) {
    float u = __expf(fv - m);
    u_buf[buf][tid] = u;
    if (tid == 1) m_slot[buf] = fv;   // lagged shift proxy for the NEXT step
    __syncthreads();
    float slot = m_slot[buf];

    // prefetch next emit (hidden behind the matvec)
    int tn = (t + 1 < len) ? (t + 1) : (len - 1);
    float e_nxt = fb[(size_t)tn * Tsz + tid];

    const float4* up = (const float4*)(u_buf[buf]);
    float s0 = 0.f, s1 = 0.f, s2 = 0.f, s3 = 0.f;
    #pragma unroll
    for (int j = 0; j < Tsz / 4; ++j) {
      float4 uv = up[j];   // wave-uniform address -> LDS broadcast read
      s0 = fmaf(er[4*j+0], uv.x, s0);
      s1 = fmaf(er[4*j+1], uv.y, s1);
      s2 = fmaf(er[4*j+2], uv.z, s2);
      s3 = fmaf(er[4*j+3], uv.w, s3);
    }
    float s = (s0 + s1) + (s2 + s3);
    // fv_new = emit + m + log(s); START row sums to 0 -> -1e30 sentinel
    fv = (s > 0.0f) ? (e_cur + m + __logf(s)) : -1e30f;
    m = fmaxf(slot, m - 30.0f);
    e_cur = e_nxt;
    buf ^= 1;
  }

  // terminal: logsumexp over next of fv + trans[START, next]
  float x = fv + trans[TAG_START * Tsz + tid];
  const int wave = tid >> 6, lane = tid & 63;
  float wm = wave_max(x);
  if (lane == 0) wred[wave] = wm;
  __syncthreads();
  float mx = fmaxf(wred[0], wred[1]);
  __syncthreads();
  float sume = wave_sum(__expf(x - mx));
  if (lane == 0) wred[wave] = sume;
  __syncthreads();
  if (tid == 0) fwd_out[b] = mx + __logf(wred[0] + wred[1]);
}

// Gold path score: one block per batch element.
__global__ __launch_bounds__(256) void crf_gold_kernel(
    const float* __restrict__ feats, const float* __restrict__ trans,
    const int* __restrict__ tags, const int* __restrict__ lens,
    float* __restrict__ gold_out)
{
  const int b = blockIdx.x;
  const int tid = threadIdx.x;
  const int len = lens[b];
  const int* tg = tags + b * Lsz;
  const float* fb = feats + (size_t)b * Lsz * Tsz;

  float acc = 0.0f;
  // transition terms: pos = 0..len inclusive
  for (int pos = tid; pos <= len; pos += 256) {
    int st = (pos == 0)   ? TAG_START : tg[pos - 1];
    int et = (pos == len) ? TAG_STOP  : tg[pos];
    acc += trans[et * Tsz + st];
  }
  // emission terms: l = 0..len-1
  for (int l = tid; l < len; l += 256) {
    acc += fb[(size_t)l * Tsz + tg[l]];
  }

  __shared__ float wred[4];
  float s = wave_sum(acc);
  int wave = tid >> 6, lane = tid & 63;
  if (lane == 0) wred[wave] = s;
  __syncthreads();
  if (tid == 0) gold_out[b] = (wred[0] + wred[1]) + (wred[2] + wred[3]);
}

// loss = mean(forward - gold)
__global__ __launch_bounds__(Bsz) void crf_final_kernel(
    const float* __restrict__ fwd, const float* __restrict__ gold,
    float* __restrict__ out)
{
  int tid = threadIdx.x;
  float v = fwd[tid] - gold[tid];
  __shared__ float wred[8];
  float s = wave_sum(v);
  int wave = tid >> 6, lane = tid & 63;
  if (lane == 0) wred[wave] = s;
  __syncthreads();
  if (tid == 0) {
    float t = 0.f;
    #pragma unroll
    for (int i = 0; i < 8; ++i) t += wred[i];
    out[0] = t * (1.0f / Bsz);
  }
}

extern "C" void kernel_launch(void* const* d_in, const int* in_sizes, int n_in,
                              void* d_out, int out_size, void* d_ws, size_t ws_size,
                              hipStream_t stream) {
  const float* feats = (const float*)d_in[0];
  const float* trans = (const float*)d_in[1];
  const int*   tags  = (const int*)d_in[2];
  const int*   lens  = (const int*)d_in[3];
  float* out  = (float*)d_out;
  float* fwd  = (float*)d_ws;
  float* gold = fwd + Bsz;

  crf_forward_kernel<<<Bsz, Tsz, 0, stream>>>(feats, trans, lens, fwd);
  crf_gold_kernel<<<Bsz, 256, 0, stream>>>(feats, trans, tags, lens, gold);
  crf_final_kernel<<<1, Bsz, 0, stream>>>(fwd, gold, out);
}